// Round 6
// baseline (444.684 us; speedup 1.0000x reference)
//
#include <hip/hip_runtime.h>
#include <cstddef>

// N=100000, E=800000, H=128, C=10, G=512
#define HD 128
#define SCAN_BS 256
#define SCAN_CHUNK 2048  // 8 elements per thread
#define QSEG 8           // partial-pool blocks per graph

typedef float f32x4 __attribute__((ext_vector_type(4)));
typedef short s16x8 __attribute__((ext_vector_type(8)));

static __device__ __forceinline__ int atomAddI(int* p, int v) {
    return __hip_atomic_fetch_add(p, v, __ATOMIC_RELAXED, __HIP_MEMORY_SCOPE_AGENT);
}

// round-to-nearest-even f32 -> bf16 bits
static __device__ __forceinline__ unsigned short rne_bf16(float f) {
    unsigned u = __float_as_uint(f);
    unsigned r = u + 0x7FFFu + ((u >> 16) & 1u);
    return (unsigned short)(r >> 16);
}
static __device__ __forceinline__ float bf16_to_f32(unsigned short h) {
    return __uint_as_float((unsigned)h << 16);
}

__global__ void k_zero_int(int* p, int n) {
    int i = blockIdx.x * blockDim.x + threadIdx.x;
    if (i < n) p[i] = 0;
}

__global__ void k_deg_int(const int* __restrict__ col, int* cnt, int E) {
    int e = blockIdx.x * blockDim.x + threadIdx.x;
    if (e < E) atomAddI(&cnt[col[e]], 1);
}

__global__ __launch_bounds__(SCAN_BS) void k_scan1(const int* __restrict__ cnt,
                                                   int* __restrict__ rowptr,
                                                   int* __restrict__ bsum, int n) {
    __shared__ int sd[SCAN_BS];
    const int t = threadIdx.x;
    const int base = blockIdx.x * SCAN_CHUNK + t * 8;
    int loc[8];
    int tsum = 0;
#pragma unroll
    for (int i = 0; i < 8; ++i) {
        loc[i] = (base + i < n) ? cnt[base + i] : 0;
        tsum += loc[i];
    }
    sd[t] = tsum;
    __syncthreads();
    for (int off = 1; off < SCAN_BS; off <<= 1) {
        int u = (t >= off) ? sd[t - off] : 0;
        __syncthreads();
        sd[t] += u;
        __syncthreads();
    }
    const int texc = sd[t] - tsum;
    if (t == SCAN_BS - 1) bsum[blockIdx.x] = sd[t];
    int pos = texc;
#pragma unroll
    for (int i = 0; i < 8; ++i) {
        if (base + i < n) rowptr[base + i] = pos;
        pos += loc[i];
    }
}

__global__ void k_scan2(int* bsum, int nblk, int* rowptr, int n) {
    if (threadIdx.x == 0 && blockIdx.x == 0) {
        int run = 0;
        for (int i = 0; i < nblk; ++i) { int v = bsum[i]; bsum[i] = run; run += v; }
        rowptr[n] = run;
    }
}

// rowptr += block offset; wofs = rowptr; dinv = rsqrt(1+cnt)
__global__ void k_scan3(int* rowptr, int* wofs, const int* __restrict__ bsum,
                        const int* __restrict__ cnt, float* __restrict__ dinv, int n) {
    int i = blockIdx.x * blockDim.x + threadIdx.x;
    if (i < n) {
        int v = rowptr[i] + bsum[i >> 11];  // SCAN_CHUNK = 2048
        rowptr[i] = v;
        wofs[i] = v;
        dinv[i] = rsqrtf(1.0f + (float)cnt[i]);
    }
}

__global__ void k_fill_csr(const int* __restrict__ rowi, const int* __restrict__ coli,
                           int* wofs, int* __restrict__ csr_src, int E) {
    int e = blockIdx.x * blockDim.x + threadIdx.x;
    if (e >= E) return;
    int p = atomAddI(&wofs[coli[e]], 1);
    csr_src[p] = rowi[e];
}

// Precompute W (128x128 f32) into MFMA B-fragment order, split hi/lo bf16.
// B-frag for 16x16x32: lane l holds B[k = kt*32+(l>>4)*8+e][col = nt*16+(l&15)].
__global__ __launch_bounds__(256) void k_wfrag(const float* __restrict__ W1,
                                               const float* __restrict__ W2,
                                               const float* __restrict__ W3,
                                               short* __restrict__ wf) {
    const int w = blockIdx.x >> 3;
    const int slot = (blockIdx.x & 7) * 256 + threadIdx.x;  // 0..2047
    const int nt = slot >> 8;
    const int kt = (slot >> 6) & 3;
    const int lane = slot & 63;
    const float* W = (w == 0) ? W1 : (w == 1) ? W2 : W3;
    short* whi = wf + (size_t)w * 32768;
    short* wlo = whi + 16384;
    const int obase = ((nt * 4 + kt) * 64 + lane) * 8;
    s16x8 hi8, lo8;
#pragma unroll
    for (int e = 0; e < 8; ++e) {
        const int k = kt * 32 + (lane >> 4) * 8 + e;
        const int c = nt * 16 + (lane & 15);
        const float v = W[(size_t)k * HD + c];
        const unsigned short h = rne_bf16(v);
        hi8[e] = (short)h;
        lo8[e] = (short)rne_bf16(v - bf16_to_f32(h));
    }
    *(s16x8*)&whi[obase] = hi8;
    *(s16x8*)&wlo[obase] = lo8;
}

static __device__ __forceinline__ void split8(const float* xs, s16x8& hi, s16x8& lo) {
#pragma unroll
    for (int e = 0; e < 8; ++e) {
        const unsigned short h = rne_bf16(xs[e]);
        hi[e] = (short)h;
        lo[e] = (short)rne_bf16(xs[e] - bf16_to_f32(h));
    }
}

// HS = dinv ⊙ (X @ W) via split-bf16 MFMA (hh + lh + hl).
// Block = 4 waves; wave computes 32 rows (2 groups of 16) x 128 cols, so each
// W-fragment load feeds 6 MFMAs. In-place safe (each wave's A loads complete
// before its stores; waves own disjoint rows).
__global__ __launch_bounds__(256) void k_gemm(const float* __restrict__ X,
                                              const short* __restrict__ whi,
                                              const short* __restrict__ wlo,
                                              const float* __restrict__ dinv,
                                              float* __restrict__ HS, int n) {
    const int lane = threadIdx.x & 63;
    const int wid = threadIdx.x >> 6;
    const int rbase = blockIdx.x * 128 + wid * 32;
    const int arow0 = min(rbase + (lane & 15), n - 1);
    const int arow1 = min(rbase + 16 + (lane & 15), n - 1);
    const int kbase = (lane >> 4) * 8;

    f32x4 acc[2][8];
#pragma unroll
    for (int g = 0; g < 2; ++g)
#pragma unroll
        for (int nt = 0; nt < 8; ++nt) acc[g][nt] = (f32x4){0.f, 0.f, 0.f, 0.f};

#pragma unroll
    for (int kt = 0; kt < 4; ++kt) {
        const float4 p0 = *(const float4*)&X[(size_t)arow0 * HD + kt * 32 + kbase];
        const float4 p1 = *(const float4*)&X[(size_t)arow0 * HD + kt * 32 + kbase + 4];
        const float4 q0 = *(const float4*)&X[(size_t)arow1 * HD + kt * 32 + kbase];
        const float4 q1 = *(const float4*)&X[(size_t)arow1 * HD + kt * 32 + kbase + 4];
        const float xs0[8] = {p0.x, p0.y, p0.z, p0.w, p1.x, p1.y, p1.z, p1.w};
        const float xs1[8] = {q0.x, q0.y, q0.z, q0.w, q1.x, q1.y, q1.z, q1.w};
        s16x8 a0hi, a0lo, a1hi, a1lo;
        split8(xs0, a0hi, a0lo);
        split8(xs1, a1hi, a1lo);
#pragma unroll
        for (int nt = 0; nt < 8; ++nt) {
            const int fo = ((nt * 4 + kt) * 64 + lane) * 8;
            const s16x8 bhi = *(const s16x8*)&whi[fo];
            const s16x8 blo = *(const s16x8*)&wlo[fo];
            acc[0][nt] = __builtin_amdgcn_mfma_f32_16x16x32_bf16(a0hi, bhi, acc[0][nt], 0, 0, 0);
            acc[1][nt] = __builtin_amdgcn_mfma_f32_16x16x32_bf16(a1hi, bhi, acc[1][nt], 0, 0, 0);
            acc[0][nt] = __builtin_amdgcn_mfma_f32_16x16x32_bf16(a0lo, bhi, acc[0][nt], 0, 0, 0);
            acc[1][nt] = __builtin_amdgcn_mfma_f32_16x16x32_bf16(a1lo, bhi, acc[1][nt], 0, 0, 0);
            acc[0][nt] = __builtin_amdgcn_mfma_f32_16x16x32_bf16(a0hi, blo, acc[0][nt], 0, 0, 0);
            acc[1][nt] = __builtin_amdgcn_mfma_f32_16x16x32_bf16(a1hi, blo, acc[1][nt], 0, 0, 0);
        }
    }

    // C/D layout: col = lane&15, row = (lane>>4)*4 + reg
    const int colb = lane & 15;
#pragma unroll
    for (int g = 0; g < 2; ++g) {
        const int rowg = rbase + g * 16 + (lane >> 4) * 4;
#pragma unroll
        for (int r = 0; r < 4; ++r) {
            const int row = rowg + r;
            if (row < n) {
                const float d = dinv[row];
#pragma unroll
                for (int nt = 0; nt < 8; ++nt)
                    HS[(size_t)row * HD + nt * 16 + colb] = acc[g][nt][r] * d;
            }
        }
    }
}

// OUT[i] = [relu]( dinv[i]*(HS[i] + sum_{e in CSR[i]} HS[src_e]) + b )
// One wave per node; each 32-lane HALF-wave gathers a full 128-f32 row as
// float4 (16B/lane), so 2 edges are processed per iteration step; 4 pairs
// (8 edges) unrolled -> 8 rows in flight per wave. Cross-half combine via
// __shfl_xor(.,32) at the end.
__global__ __launch_bounds__(256) void k_gather(const int* __restrict__ rowptr,
                                                const int* __restrict__ csr_src,
                                                const float* __restrict__ HS,
                                                const float* __restrict__ dinv,
                                                const float* __restrict__ b,
                                                float* __restrict__ OUT,
                                                int n, int relu) {
    const int node = __builtin_amdgcn_readfirstlane(blockIdx.x * 4 + (threadIdx.x >> 6));
    if (node >= n) return;
    const int lane = threadIdx.x & 63;
    const int half = lane >> 5;
    const int j = (lane & 31) * 4;

    // self loop: count once (half 0 only)
    const float4 s4 = *(const float4*)&HS[(size_t)node * HD + j];
    f32x4 acc = half ? (f32x4){0.f, 0.f, 0.f, 0.f}
                     : (f32x4){s4.x, s4.y, s4.z, s4.w};

    const int s = rowptr[node];
    const int e = rowptr[node + 1];
    int k = s;
    for (; k + 8 <= e; k += 8) {
        int idx[8];
#pragma unroll
        for (int u = 0; u < 8; ++u) idx[u] = csr_src[k + u];
#pragma unroll
        for (int p = 0; p < 4; ++p) {
            const int src = idx[p * 2 + half];
            const float4 v = *(const float4*)&HS[(size_t)src * HD + j];
            acc.x += v.x; acc.y += v.y; acc.z += v.z; acc.w += v.w;
        }
    }
    for (; k + 2 <= e; k += 2) {
        const int src = csr_src[k + half];
        const float4 v = *(const float4*)&HS[(size_t)src * HD + j];
        acc.x += v.x; acc.y += v.y; acc.z += v.z; acc.w += v.w;
    }
    if (k < e) {  // single leftover edge: half 0 only
        const int src = csr_src[k];
        const float4 v = *(const float4*)&HS[(size_t)src * HD + j];
        if (!half) { acc.x += v.x; acc.y += v.y; acc.z += v.z; acc.w += v.w; }
    }

    // combine halves
    acc.x += __shfl_xor(acc.x, 32);
    acc.y += __shfl_xor(acc.y, 32);
    acc.z += __shfl_xor(acc.z, 32);
    acc.w += __shfl_xor(acc.w, 32);

    if (half == 0) {
        const float d = dinv[node];
        const float4 bv = *(const float4*)&b[j];
        float ox = fmaf(acc.x, d, bv.x);
        float oy = fmaf(acc.y, d, bv.y);
        float oz = fmaf(acc.z, d, bv.z);
        float ow = fmaf(acc.w, d, bv.w);
        if (relu) {
            ox = fmaxf(ox, 0.f); oy = fmaxf(oy, 0.f);
            oz = fmaxf(oz, 0.f); ow = fmaxf(ow, 0.f);
        }
        *(float4*)&OUT[(size_t)node * HD + j] = make_float4(ox, oy, oz, ow);
    }
}

// Stage 1 pooling: QSEG blocks per graph.
__global__ __launch_bounds__(128) void k_pool_part(const float* __restrict__ X,
                                                   const int* __restrict__ batch,
                                                   float* __restrict__ psum, int n) {
    const int g = blockIdx.x / QSEG;
    const int q = blockIdx.x % QSEG;
    const int t = threadIdx.x;
    int lo = 0, hi = n;
    while (lo < hi) { int m = (lo + hi) >> 1; if (batch[m] < g) lo = m + 1; else hi = m; }
    const int start = lo;
    hi = n;
    while (lo < hi) { int m = (lo + hi) >> 1; if (batch[m] < g + 1) lo = m + 1; else hi = m; }
    const int end = lo;
    float acc = 0.f;
    for (int i = start + q; i < end; i += QSEG) acc += X[(size_t)i * HD + t];
    psum[(size_t)blockIdx.x * HD + t] = acc;
}

// Stage 2 + final linear fused.
__global__ __launch_bounds__(128) void k_pool_final(const float* __restrict__ psum,
                                                    const int* __restrict__ batch,
                                                    const float* __restrict__ Wl,
                                                    const float* __restrict__ bl,
                                                    float* __restrict__ out, int n, int C) {
    __shared__ float pl[HD];
    const int g = blockIdx.x;
    const int t = threadIdx.x;
    int lo = 0, hi = n;
    while (lo < hi) { int m = (lo + hi) >> 1; if (batch[m] < g) lo = m + 1; else hi = m; }
    const int start = lo;
    hi = n;
    while (lo < hi) { int m = (lo + hi) >> 1; if (batch[m] < g + 1) lo = m + 1; else hi = m; }
    const int cnt = lo - start;
    float acc = 0.f;
#pragma unroll
    for (int q = 0; q < QSEG; ++q)
        acc += psum[((size_t)g * QSEG + q) * HD + t];
    pl[t] = acc / (float)max(cnt, 1);
    __syncthreads();
    if (t < C) {
        float s = 0.f;
        for (int k = 0; k < HD; ++k)
            s = fmaf(pl[k], Wl[(size_t)k * C + t], s);
        out[(size_t)g * C + t] = s + bl[t];
    }
}

extern "C" void kernel_launch(void* const* d_in, const int* in_sizes, int n_in,
                              void* d_out, int out_size, void* d_ws, size_t ws_size,
                              hipStream_t stream) {
    const float* x   = (const float*)d_in[0];
    const int* ei    = (const int*)d_in[1];
    const int* batch = (const int*)d_in[2];
    const float* W1 = (const float*)d_in[3];
    const float* b1 = (const float*)d_in[4];
    const float* W2 = (const float*)d_in[5];
    const float* b2 = (const float*)d_in[6];
    const float* W3 = (const float*)d_in[7];
    const float* b3 = (const float*)d_in[8];
    const float* Wl = (const float*)d_in[9];
    const float* bl = (const float*)d_in[10];
    float* out = (float*)d_out;

    const int N = in_sizes[0] / HD;
    const int E = in_sizes[1] / 2;
    const int C = 10;
    const int G = out_size / C;

    const int* rowi = ei;      // sources
    const int* coli = ei + E;  // targets

    // workspace layout
    float* B0     = (float*)d_ws;                    // N*HD
    float* B1     = B0 + (size_t)N * HD;             // N*HD
    float* dinv   = B1 + (size_t)N * HD;             // N
    short* wf     = (short*)(dinv + N);              // 3*2*16384 shorts
    int* rowptr   = (int*)(wf + 3 * 32768);          // N+1
    int* wofs     = rowptr + (N + 1);                // N
    int* cnt      = wofs + N;                        // N
    int* bsum     = cnt + N;                         // 64
    int* csr_src  = bsum + 64;                       // E
    float* psum   = B0;  // G*QSEG*HD floats — B0 is dead after layer 3

    const int T = 256;
    const int nblk = (N + SCAN_CHUNK - 1) / SCAN_CHUNK;

    // ---- preprocessing: CSR, dinv, W fragments ----
    k_zero_int<<<(N + T - 1) / T, T, 0, stream>>>(cnt, N);
    k_deg_int<<<(E + T - 1) / T, T, 0, stream>>>(coli, cnt, E);
    k_scan1<<<nblk, SCAN_BS, 0, stream>>>(cnt, rowptr, bsum, N);
    k_scan2<<<1, 64, 0, stream>>>(bsum, nblk, rowptr, N);
    k_scan3<<<(N + T - 1) / T, T, 0, stream>>>(rowptr, wofs, bsum, cnt, dinv, N);
    k_fill_csr<<<(E + T - 1) / T, T, 0, stream>>>(rowi, coli, wofs, csr_src, E);
    k_wfrag<<<24, 256, 0, stream>>>(W1, W2, W3, wf);

    const short* whi1 = wf;                const short* wlo1 = wf + 16384;
    const short* whi2 = wf + 32768;        const short* wlo2 = wf + 49152;
    const short* whi3 = wf + 65536;        const short* wlo3 = wf + 81920;

    const int gGemm   = (N + 127) / 128;
    const int gGather = (N + 3) / 4;

    // Layer 1: x -> HS=B0 -> X1=B1
    k_gemm<<<gGemm, T, 0, stream>>>(x, whi1, wlo1, dinv, B0, N);
    k_gather<<<gGather, T, 0, stream>>>(rowptr, csr_src, B0, dinv, b1, B1, N, 1);

    // Layer 2: B1 -> HS=B1 (alias-safe) -> X2=B0
    k_gemm<<<gGemm, T, 0, stream>>>(B1, whi2, wlo2, dinv, B1, N);
    k_gather<<<gGather, T, 0, stream>>>(rowptr, csr_src, B1, dinv, b2, B0, N, 1);

    // Layer 3: B0 -> HS=B0 (alias-safe) -> X3=B1 (no relu)
    k_gemm<<<gGemm, T, 0, stream>>>(B0, whi3, wlo3, dinv, B0, N);
    k_gather<<<gGather, T, 0, stream>>>(rowptr, csr_src, B0, dinv, b3, B1, N, 0);

    // Two-stage pool + fused final linear (psum aliases B0, now dead)
    k_pool_part<<<G * QSEG, 128, 0, stream>>>(B1, batch, psum, N);
    k_pool_final<<<G, 128, 0, stream>>>(psum, batch, Wl, bl, out, N, C);
}